// Round 2
// baseline (255.394 us; speedup 1.0000x reference)
//
#include <hip/hip_runtime.h>

typedef unsigned short u16;
typedef __attribute__((ext_vector_type(8))) short short8;
typedef __attribute__((ext_vector_type(4))) float floatx4;

__device__ __forceinline__ u16 f2bf(float f) {
  union { float f; unsigned u; } v; v.f = f;
  unsigned r = v.u + 0x7fffu + ((v.u >> 16) & 1u);
  return (u16)(r >> 16);
}

__device__ __forceinline__ floatx4 mfma16(short8 a, short8 b, floatx4 c) {
  return __builtin_amdgcn_mfma_f32_16x16x32_bf16(a, b, c, 0, 0, 0);
}

#define AS1 __attribute__((address_space(1)))
#define AS3 __attribute__((address_space(3)))
__device__ __forceinline__ void gload_lds16(const u16* g, u16* l) {
  __builtin_amdgcn_global_load_lds((const AS1 void*)g, (AS3 void*)l, 16, 0, 0);
}

// ---------------- convert: f32 -> bf16, 8 elems/thread ---------------------
__global__ void __launch_bounds__(256) f32_to_bf16_vec(
    const float* __restrict__ in, u16* __restrict__ out) {
  const int i = blockIdx.x * 256 + threadIdx.x;
  const float4* p = (const float4*)in + (size_t)i * 2;
  float4 a = p[0], b = p[1];
  short8 o;
  o[0] = (short)f2bf(a.x); o[1] = (short)f2bf(a.y);
  o[2] = (short)f2bf(a.z); o[3] = (short)f2bf(a.w);
  o[4] = (short)f2bf(b.x); o[5] = (short)f2bf(b.y);
  o[6] = (short)f2bf(b.z); o[7] = (short)f2bf(b.w);
  *(short8*)(out + (size_t)i * 8) = o;
}

// -------- transpose+convert: in f32 [R][C] -> out bf16 [C][R], 64x64 tiles --
__global__ void __launch_bounds__(256) transpose_f32_to_bf16(
    const float* __restrict__ in, u16* __restrict__ out, int R, int C) {
  __shared__ float tile[64][65];
  const int c0 = blockIdx.x * 64, r0 = blockIdx.y * 64;
  const int t = threadIdx.x;
  const int rr = t >> 2, cc = (t & 3) * 16;
  const float* src = in + (size_t)(r0 + rr) * C + (c0 + cc);
  float4 v0 = *(const float4*)(src);
  float4 v1 = *(const float4*)(src + 4);
  float4 v2 = *(const float4*)(src + 8);
  float4 v3 = *(const float4*)(src + 12);
  tile[rr][cc + 0] = v0.x;  tile[rr][cc + 1] = v0.y;
  tile[rr][cc + 2] = v0.z;  tile[rr][cc + 3] = v0.w;
  tile[rr][cc + 4] = v1.x;  tile[rr][cc + 5] = v1.y;
  tile[rr][cc + 6] = v1.z;  tile[rr][cc + 7] = v1.w;
  tile[rr][cc + 8] = v2.x;  tile[rr][cc + 9] = v2.y;
  tile[rr][cc + 10] = v2.z; tile[rr][cc + 11] = v2.w;
  tile[rr][cc + 12] = v3.x; tile[rr][cc + 13] = v3.y;
  tile[rr][cc + 14] = v3.z; tile[rr][cc + 15] = v3.w;
  __syncthreads();
  short8 w0, w1;
#pragma unroll
  for (int i = 0; i < 8; ++i) {
    w0[i] = (short)f2bf(tile[cc + i][rr]);
    w1[i] = (short)f2bf(tile[cc + 8 + i][rr]);
  }
  u16* dst = out + (size_t)(c0 + rr) * R + (r0 + cc);
  *(short8*)dst = w0;
  *(short8*)(dst + 8) = w1;
}

// ---------------- GEMM: C[M,N] = A[M,K] * Bt[N,K]^T + bias -----------------
// A, Bt bf16; bias f32.
// EPI==0: scatter bf16 into Q[B,H,S,64] (O0), K[B,H,S,64] (O1), Vt[B,H,64,S] (O2)
// EPI==1: f32 row-major write to Of [M,N]
template <int EPI>
__global__ void __launch_bounds__(256) gemm_bt(
    const u16* __restrict__ A, const u16* __restrict__ Bt,
    const float* __restrict__ bias, u16* __restrict__ O0,
    u16* __restrict__ O1, u16* __restrict__ O2, float* __restrict__ Of,
    int M, int N, int K) {
  __shared__ u16 As[4096];  // [128 rows][32 k]
  __shared__ u16 Bs[4096];  // [128 cols][32 k]
  const int t = threadIdx.x, w = t >> 6, l = t & 63;
  const int lo = l & 15, g = l >> 4;
  const int wr = w >> 1, wc = w & 1;
  const int m0 = blockIdx.y * 128, n0 = blockIdx.x * 128;
  const int sr = l >> 2, sc = (l & 3) * 8;
  const u16* Ag = A + (size_t)(m0 + w * 16 + sr) * K + sc;
  const u16* Bg = Bt + (size_t)(n0 + w * 16 + sr) * K + sc;
  u16* AsW = As + w * 512;
  u16* BsW = Bs + w * 512;

  floatx4 acc[4][4] = {};
  for (int k0 = 0; k0 < K; k0 += 32) {
    gload_lds16(Ag + k0, AsW);
    gload_lds16(Ag + (size_t)64 * K + k0, AsW + 2048);
    gload_lds16(Bg + k0, BsW);
    gload_lds16(Bg + (size_t)64 * K + k0, BsW + 2048);
    __syncthreads();
    short8 af[4], bff[4];
#pragma unroll
    for (int m = 0; m < 4; ++m)
      af[m] = *(const short8*)(As + (wr * 64 + m * 16 + lo) * 32 + g * 8);
#pragma unroll
    for (int n = 0; n < 4; ++n)
      bff[n] = *(const short8*)(Bs + (wc * 64 + n * 16 + lo) * 32 + g * 8);
#pragma unroll
    for (int m = 0; m < 4; ++m)
#pragma unroll
      for (int n = 0; n < 4; ++n) acc[m][n] = mfma16(af[m], bff[n], acc[m][n]);
    __syncthreads();
  }

#pragma unroll
  for (int m = 0; m < 4; ++m) {
    const int row_base = m0 + wr * 64 + m * 16 + g * 4;
#pragma unroll
    for (int n = 0; n < 4; ++n) {
      const int col = n0 + wc * 64 + n * 16 + lo;
      const float bv = bias[col];
#pragma unroll
      for (int j = 0; j < 4; ++j) {
        const int r = row_base + j;
        const float v = acc[m][n][j] + bv;
        if (EPI == 0) {
          const u16 h = f2bf(v);
          const int b = r >> 11, s = r & 2047;
          int c = col;
          if (c < 1024) {
            const int hh = c >> 6, d = c & 63;
            O0[(((size_t)(b * 16 + hh)) * 2048 + s) * 64 + d] = h;
          } else if (c < 2048) {
            c -= 1024;
            const int hh = c >> 6, d = c & 63;
            O1[(((size_t)(b * 16 + hh)) * 2048 + s) * 64 + d] = h;
          } else {
            c -= 2048;
            const int hh = c >> 6, d = c & 63;
            O2[(((size_t)(b * 16 + hh)) * 64 + d) * 2048 + s] = h;
          }
        } else {
          Of[(size_t)r * N + col] = v;
        }
      }
    }
  }
}

// ---------------- causal flash attention --------------------------------
// Q,K: [B*H, S, 64] bf16 row-major; Vt: [B*H, 64, S] bf16; O: [B, S, 1024] bf16
__global__ void __launch_bounds__(64) attn_kernel(
    const u16* __restrict__ Q, const u16* __restrict__ K,
    const u16* __restrict__ Vt, u16* __restrict__ O) {
  const int S = 2048;
  __shared__ u16 Plds[32 * 32];
  const int l = threadIdx.x, lo = l & 15, g = l >> 4;
  const int q0 = blockIdx.x * 32;
  const int bh = blockIdx.y;  // b*16 + h
  const u16* Qb = Q + (size_t)bh * S * 64;
  const u16* Kb = K + (size_t)bh * S * 64;
  const u16* Vb = Vt + (size_t)bh * 64 * S;

  short8 aq[2][2];
#pragma unroll
  for (int m = 0; m < 2; ++m)
#pragma unroll
    for (int kk = 0; kk < 2; ++kk)
      aq[m][kk] =
          *(const short8*)(Qb + (size_t)(q0 + m * 16 + lo) * 64 + kk * 32 + g * 8);

  float mrow[8], lrow[8];
#pragma unroll
  for (int i = 0; i < 8; ++i) {
    mrow[i] = -1e30f;
    lrow[i] = 0.f;
  }
  floatx4 o[2][4] = {};

  const int ntiles = (q0 >> 5) + 1;
  for (int tt = 0; tt < ntiles; ++tt) {
    const int kv0 = tt * 32;
    short8 bk[2][2];
#pragma unroll
    for (int n = 0; n < 2; ++n)
#pragma unroll
      for (int kk = 0; kk < 2; ++kk)
        bk[n][kk] = *(const short8*)(Kb + (size_t)(kv0 + n * 16 + lo) * 64 +
                                     kk * 32 + g * 8);
    floatx4 s[2][2] = {};
#pragma unroll
    for (int m = 0; m < 2; ++m)
#pragma unroll
      for (int n = 0; n < 2; ++n)
#pragma unroll
        for (int kk = 0; kk < 2; ++kk)
          s[m][n] = mfma16(aq[m][kk], bk[n][kk], s[m][n]);

    const bool diag = (tt == ntiles - 1);
    float p[2][2][4];
#pragma unroll
    for (int m = 0; m < 2; ++m)
#pragma unroll
      for (int n = 0; n < 2; ++n)
#pragma unroll
        for (int j = 0; j < 4; ++j) {
          float v = s[m][n][j] * 0.125f;
          if (diag && (n * 16 + lo) > (m * 16 + g * 4 + j)) v = -1e30f;
          p[m][n][j] = v;
        }
    float tmax[8];
#pragma unroll
    for (int m = 0; m < 2; ++m)
#pragma unroll
      for (int j = 0; j < 4; ++j)
        tmax[m * 4 + j] = fmaxf(p[m][0][j], p[m][1][j]);
#pragma unroll
    for (int msk = 1; msk <= 8; msk <<= 1)
#pragma unroll
      for (int r = 0; r < 8; ++r)
        tmax[r] = fmaxf(tmax[r], __shfl_xor(tmax[r], msk));
    float corr[8];
#pragma unroll
    for (int r = 0; r < 8; ++r) {
      const float mn = fmaxf(mrow[r], tmax[r]);
      corr[r] = __expf(mrow[r] - mn);
      mrow[r] = mn;
    }
    float rsum[8];
#pragma unroll
    for (int r = 0; r < 8; ++r) rsum[r] = 0.f;
#pragma unroll
    for (int m = 0; m < 2; ++m)
#pragma unroll
      for (int n = 0; n < 2; ++n)
#pragma unroll
        for (int j = 0; j < 4; ++j) {
          const float e = __expf(p[m][n][j] - mrow[m * 4 + j]);
          p[m][n][j] = e;
          rsum[m * 4 + j] += e;
        }
#pragma unroll
    for (int msk = 1; msk <= 8; msk <<= 1)
#pragma unroll
      for (int r = 0; r < 8; ++r) rsum[r] += __shfl_xor(rsum[r], msk);
#pragma unroll
    for (int r = 0; r < 8; ++r) lrow[r] = lrow[r] * corr[r] + rsum[r];
#pragma unroll
    for (int m = 0; m < 2; ++m)
#pragma unroll
      for (int c = 0; c < 4; ++c)
#pragma unroll
        for (int j = 0; j < 4; ++j) o[m][c][j] *= corr[m * 4 + j];
#pragma unroll
    for (int m = 0; m < 2; ++m)
#pragma unroll
      for (int n = 0; n < 2; ++n)
#pragma unroll
        for (int j = 0; j < 4; ++j)
          Plds[(m * 16 + g * 4 + j) * 32 + n * 16 + lo] = f2bf(p[m][n][j]);
    __syncthreads();
    short8 pa[2];
#pragma unroll
    for (int m = 0; m < 2; ++m)
      pa[m] = *(const short8*)(Plds + (m * 16 + lo) * 32 + g * 8);
    short8 bv[4];
#pragma unroll
    for (int c = 0; c < 4; ++c)
      bv[c] = *(const short8*)(Vb + (size_t)(c * 16 + lo) * S + kv0 + g * 8);
#pragma unroll
    for (int m = 0; m < 2; ++m)
#pragma unroll
      for (int c = 0; c < 4; ++c) o[m][c] = mfma16(pa[m], bv[c], o[m][c]);
    __syncthreads();
  }

  const int b = bh >> 4, h = bh & 15;
#pragma unroll
  for (int m = 0; m < 2; ++m)
#pragma unroll
    for (int c = 0; c < 4; ++c)
#pragma unroll
      for (int j = 0; j < 4; ++j) {
        const int r = q0 + m * 16 + g * 4 + j;
        const int d = c * 16 + lo;
        const float v = o[m][c][j] / lrow[m * 4 + j];
        O[((size_t)(b * 2048 + r)) * 1024 + h * 64 + d] = f2bf(v);
      }
}

extern "C" void kernel_launch(void* const* d_in, const int* in_sizes, int n_in,
                              void* d_out, int out_size, void* d_ws,
                              size_t ws_size, hipStream_t stream) {
  const float* x = (const float*)d_in[0];       // [4096, 1024] f32
  const float* w_qkv = (const float*)d_in[1];   // [1024, 3072] f32
  const float* b_qkv = (const float*)d_in[2];   // [3072] f32
  const float* w_proj = (const float*)d_in[3];  // [1024, 1024] f32
  const float* b_proj = (const float*)d_in[4];  // [1024] f32
  float* out = (float*)d_out;                   // [4096, 1024] f32

  char* ws = (char*)d_ws;
  u16* Xb = (u16*)(ws);                      // [4096,1024] bf16  8 MB
  u16* WqkvT = (u16*)(ws + 8388608);         // [3072,1024] bf16  6 MB
  u16* WprojT = (u16*)(ws + 14680064);       // [1024,1024] bf16  2 MB
  u16* Qw = (u16*)(ws + 16777216);           // [32,2048,64] bf16 8 MB
  u16* Kw = (u16*)(ws + 25165824);           // [32,2048,64] bf16 8 MB
  u16* Vtw = (u16*)(ws + 33554432);          // [32,64,2048] bf16 8 MB
  u16* AttnO = Xb;                           // overlay: Xb dead after GEMM1

  f32_to_bf16_vec<<<2048, 256, 0, stream>>>(x, Xb);
  transpose_f32_to_bf16<<<dim3(48, 16), 256, 0, stream>>>(w_qkv, WqkvT, 1024,
                                                          3072);
  transpose_f32_to_bf16<<<dim3(16, 16), 256, 0, stream>>>(w_proj, WprojT, 1024,
                                                          1024);
  gemm_bt<0><<<dim3(24, 32), 256, 0, stream>>>(Xb, WqkvT, b_qkv, Qw, Kw, Vtw,
                                               nullptr, 4096, 3072, 1024);
  attn_kernel<<<dim3(64, 32), 64, 0, stream>>>(Qw, Kw, Vtw, AttnO);
  gemm_bt<1><<<dim3(8, 32), 256, 0, stream>>>(AttnO, WprojT, b_proj, nullptr,
                                              nullptr, nullptr, out, 4096, 1024,
                                              1024);
}

// Round 4
// 174.718 us; speedup vs baseline: 1.4617x; 1.4617x over previous
//
#include <hip/hip_runtime.h>
#include <hip/hip_bf16.h>

typedef unsigned short u16;
typedef __attribute__((ext_vector_type(8))) short short8;
typedef __attribute__((ext_vector_type(4))) float floatx4;
typedef __attribute__((ext_vector_type(16))) float floatx16;

__device__ __forceinline__ u16 f2bf(float f) {
  union { float f; unsigned u; } v; v.f = f;
  unsigned r = v.u + 0x7fffu + ((v.u >> 16) & 1u);
  return (u16)(r >> 16);
}

__device__ __forceinline__ floatx4 mfma16(short8 a, short8 b, floatx4 c) {
  return __builtin_amdgcn_mfma_f32_16x16x32_bf16(a, b, c, 0, 0, 0);
}
__device__ __forceinline__ floatx16 mfma32(short8 a, short8 b, floatx16 c) {
  return __builtin_amdgcn_mfma_f32_32x32x16_bf16(a, b, c, 0, 0, 0);
}

#define AS1 __attribute__((address_space(1)))
#define AS3 __attribute__((address_space(3)))
__device__ __forceinline__ void gload_lds16(const u16* g, u16* l) {
  __builtin_amdgcn_global_load_lds((const AS1 void*)g, (AS3 void*)l, 16, 0, 0);
}

// pack two f32 -> u32 of 2 bf16 (compiler emits v_cvt_pk_bf16_f32)
__device__ __forceinline__ unsigned pack2(float a, float b) {
  union { __hip_bfloat162 h; unsigned u; } x;
  x.h = __hip_bfloat162(__float2bfloat16(a), __float2bfloat16(b));
  return x.u;
}

// ---------------- convert: f32 -> bf16, 8 elems/thread ---------------------
__global__ void __launch_bounds__(256) f32_to_bf16_vec(
    const float* __restrict__ in, u16* __restrict__ out) {
  const int i = blockIdx.x * 256 + threadIdx.x;
  const float4* p = (const float4*)in + (size_t)i * 2;
  float4 a = p[0], b = p[1];
  short8 o;
  o[0] = (short)f2bf(a.x); o[1] = (short)f2bf(a.y);
  o[2] = (short)f2bf(a.z); o[3] = (short)f2bf(a.w);
  o[4] = (short)f2bf(b.x); o[5] = (short)f2bf(b.y);
  o[6] = (short)f2bf(b.z); o[7] = (short)f2bf(b.w);
  *(short8*)(out + (size_t)i * 8) = o;
}

// -------- transpose+convert: in f32 [R][C] -> out bf16 [C][R], 64x64 tiles --
__global__ void __launch_bounds__(256) transpose_f32_to_bf16(
    const float* __restrict__ in, u16* __restrict__ out, int R, int C) {
  __shared__ float tile[64][65];
  const int c0 = blockIdx.x * 64, r0 = blockIdx.y * 64;
  const int t = threadIdx.x;
  const int rr = t >> 2, cc = (t & 3) * 16;
  const float* src = in + (size_t)(r0 + rr) * C + (c0 + cc);
  float4 v0 = *(const float4*)(src);
  float4 v1 = *(const float4*)(src + 4);
  float4 v2 = *(const float4*)(src + 8);
  float4 v3 = *(const float4*)(src + 12);
  tile[rr][cc + 0] = v0.x;  tile[rr][cc + 1] = v0.y;
  tile[rr][cc + 2] = v0.z;  tile[rr][cc + 3] = v0.w;
  tile[rr][cc + 4] = v1.x;  tile[rr][cc + 5] = v1.y;
  tile[rr][cc + 6] = v1.z;  tile[rr][cc + 7] = v1.w;
  tile[rr][cc + 8] = v2.x;  tile[rr][cc + 9] = v2.y;
  tile[rr][cc + 10] = v2.z; tile[rr][cc + 11] = v2.w;
  tile[rr][cc + 12] = v3.x; tile[rr][cc + 13] = v3.y;
  tile[rr][cc + 14] = v3.z; tile[rr][cc + 15] = v3.w;
  __syncthreads();
  short8 w0, w1;
#pragma unroll
  for (int i = 0; i < 8; ++i) {
    w0[i] = (short)f2bf(tile[cc + i][rr]);
    w1[i] = (short)f2bf(tile[cc + 8 + i][rr]);
  }
  u16* dst = out + (size_t)(c0 + rr) * R + (r0 + cc);
  *(short8*)dst = w0;
  *(short8*)(dst + 8) = w1;
}

// ---------------- GEMM: C[M,N] = A[M,K] * Bt[N,K]^T + bias -----------------
template <int EPI>
__global__ void __launch_bounds__(256) gemm_bt(
    const u16* __restrict__ A, const u16* __restrict__ Bt,
    const float* __restrict__ bias, u16* __restrict__ O0,
    u16* __restrict__ O1, u16* __restrict__ O2, float* __restrict__ Of,
    int M, int N, int K) {
  __shared__ u16 As[4096];
  __shared__ u16 Bs[4096];
  const int t = threadIdx.x, w = t >> 6, l = t & 63;
  const int lo = l & 15, g = l >> 4;
  const int wr = w >> 1, wc = w & 1;
  const int m0 = blockIdx.y * 128, n0 = blockIdx.x * 128;
  const int sr = l >> 2, sc = (l & 3) * 8;
  const u16* Ag = A + (size_t)(m0 + w * 16 + sr) * K + sc;
  const u16* Bg = Bt + (size_t)(n0 + w * 16 + sr) * K + sc;
  u16* AsW = As + w * 512;
  u16* BsW = Bs + w * 512;

  floatx4 acc[4][4] = {};
  for (int k0 = 0; k0 < K; k0 += 32) {
    gload_lds16(Ag + k0, AsW);
    gload_lds16(Ag + (size_t)64 * K + k0, AsW + 2048);
    gload_lds16(Bg + k0, BsW);
    gload_lds16(Bg + (size_t)64 * K + k0, BsW + 2048);
    __syncthreads();
    short8 af[4], bff[4];
#pragma unroll
    for (int m = 0; m < 4; ++m)
      af[m] = *(const short8*)(As + (wr * 64 + m * 16 + lo) * 32 + g * 8);
#pragma unroll
    for (int n = 0; n < 4; ++n)
      bff[n] = *(const short8*)(Bs + (wc * 64 + n * 16 + lo) * 32 + g * 8);
#pragma unroll
    for (int m = 0; m < 4; ++m)
#pragma unroll
      for (int n = 0; n < 4; ++n) acc[m][n] = mfma16(af[m], bff[n], acc[m][n]);
    __syncthreads();
  }

#pragma unroll
  for (int m = 0; m < 4; ++m) {
    const int row_base = m0 + wr * 64 + m * 16 + g * 4;
#pragma unroll
    for (int n = 0; n < 4; ++n) {
      const int col = n0 + wc * 64 + n * 16 + lo;
      const float bv = bias[col];
#pragma unroll
      for (int j = 0; j < 4; ++j) {
        const int r = row_base + j;
        const float v = acc[m][n][j] + bv;
        if (EPI == 0) {
          const u16 h = f2bf(v);
          const int b = r >> 11, s = r & 2047;
          int c = col;
          if (c < 1024) {
            const int hh = c >> 6, d = c & 63;
            O0[(((size_t)(b * 16 + hh)) * 2048 + s) * 64 + d] = h;
          } else if (c < 2048) {
            c -= 1024;
            const int hh = c >> 6, d = c & 63;
            O1[(((size_t)(b * 16 + hh)) * 2048 + s) * 64 + d] = h;
          } else {
            c -= 2048;
            const int hh = c >> 6, d = c & 63;
            O2[(((size_t)(b * 16 + hh)) * 64 + d) * 2048 + s] = h;
          }
        } else {
          Of[(size_t)r * N + col] = v;
        }
      }
    }
  }
}

// ---------------- causal flash attention (4-wave, swapped 32x32) ----------
// Q,K: [B*H, S, 64] bf16; Vt: [B*H, 64, S] bf16; O: [B, S, 1024] bf16
__global__ void __launch_bounds__(256, 2) attn_kernel(
    const u16* __restrict__ Q, const u16* __restrict__ K,
    const u16* __restrict__ Vt, u16* __restrict__ O) {
  const int S = 2048;
  __shared__ u16 smem[2][8192];  // per buf: K tile [64][64] | V tile [64][64]
  const int t = threadIdx.x, w = t >> 6, l = t & 63;
  const int lo = l & 31, h = l >> 5;
  const int fid = blockIdx.x;
  const int half = fid >> 8, rdec = fid & 255;
  const int bh = half * 16 + (rdec >> 4);
  const int qb = half ? (15 - (rdec & 15)) : (rdec & 15);
  const int q0w = qb * 128 + w * 32;
  const int qmax = q0w + 31;
  const int qabs = q0w + lo;
  const u16* Qb = Q + (size_t)bh * S * 64;
  const u16* Kb = K + (size_t)bh * S * 64;
  const u16* Vb = Vt + (size_t)bh * 64 * S;

  short8 qf[4];
#pragma unroll
  for (int ks = 0; ks < 4; ++ks)
    qf[ks] = *(const short8*)(Qb + (size_t)(q0w + lo) * 64 + ks * 16 + h * 8);

  floatx16 o0 = {}, o1 = {};
  float m2 = -1e30f, ll = 0.f;

  auto STAGE = [&](int buf, int kv0) {
#pragma unroll
    for (int i = 0; i < 2; ++i) {
      const int idx = i * 256 + t;
      const int rw = idx >> 3;
      const int cg = (idx & 7) ^ (rw & 7);  // pre-swizzled global chunk
      gload_lds16(Kb + (size_t)(kv0 + rw) * 64 + cg * 8,
                  &smem[buf][i * 2048 + w * 512]);
      gload_lds16(Vb + (size_t)rw * S + kv0 + cg * 8,
                  &smem[buf][4096 + i * 2048 + w * 512]);
    }
  };

  const int T = 2 * (qb + 1);
  STAGE(0, 0);
  __syncthreads();
  int cur = 0;
  for (int tt = 0; tt < T; ++tt) {
    const int kv0 = tt * 64;
    if (tt + 1 < T) STAGE(cur ^ 1, (tt + 1) * 64);
    if (kv0 <= qmax) {
      floatx16 st0 = {}, st1 = {};
#pragma unroll
      for (int ks = 0; ks < 4; ++ks) {
        const int r0 = lo;
        short8 kf0 = *(const short8*)(
            &smem[cur][r0 * 64 + ((ks * 16 + h * 8) ^ ((r0 & 7) << 3))]);
        st0 = mfma32(kf0, qf[ks], st0);
        const int r1 = 32 + lo;
        short8 kf1 = *(const short8*)(
            &smem[cur][r1 * 64 + ((ks * 16 + h * 8) ^ ((r1 & 7) << 3))]);
        st1 = mfma32(kf1, qf[ks], st1);
      }
      // masking needed iff tile reaches past the wave's MINIMUM q (q0w)
      const bool diag = (kv0 + 63 > q0w);
      float p[2][16];
      float tmax = -1e30f;
#pragma unroll
      for (int rr = 0; rr < 16; ++rr) {
        float v0 = st0[rr] * 0.125f;
        float v1 = st1[rr] * 0.125f;
        if (diag) {
          const int kvr = kv0 + (rr & 3) + 8 * (rr >> 2) + 4 * h;
          if (kvr > qabs) v0 = -1e30f;
          if (kvr + 32 > qabs) v1 = -1e30f;
        }
        p[0][rr] = v0;
        p[1][rr] = v1;
        tmax = fmaxf(tmax, fmaxf(v0, v1));
      }
      tmax = fmaxf(tmax, __shfl_xor(tmax, 32));
      const float mnew = fmaxf(m2, tmax);
      const float corr = __expf(m2 - mnew);
      m2 = mnew;
      float tsum = 0.f;
#pragma unroll
      for (int nt = 0; nt < 2; ++nt)
#pragma unroll
        for (int rr = 0; rr < 16; ++rr) {
          const float e = __expf(p[nt][rr] - m2);
          p[nt][rr] = e;
          tsum += e;
        }
      tsum += __shfl_xor(tsum, 32);
      ll = ll * corr + tsum;
      o0 = o0 * corr;
      o1 = o1 * corr;
#pragma unroll
      for (int s = 0; s < 4; ++s) {
        const int ts = s >> 1, rb = (s & 1) * 8;
        const unsigned wA = pack2(p[ts][rb + 0], p[ts][rb + 1]);
        const unsigned wB = pack2(p[ts][rb + 2], p[ts][rb + 3]);
        const unsigned wC = pack2(p[ts][rb + 4], p[ts][rb + 5]);
        const unsigned wD = pack2(p[ts][rb + 6], p[ts][rb + 7]);
        const unsigned sA = (unsigned)__shfl_xor((int)wA, 32);
        const unsigned sB = (unsigned)__shfl_xor((int)wB, 32);
        const unsigned sC = (unsigned)__shfl_xor((int)wC, 32);
        const unsigned sD = (unsigned)__shfl_xor((int)wD, 32);
        union { unsigned u[4]; short8 s8; } bf;
        bf.u[0] = h ? sC : wA;
        bf.u[1] = h ? sD : wB;
        bf.u[2] = h ? wC : sA;
        bf.u[3] = h ? wD : sB;
        {
          const int r0 = lo;
          short8 vf = *(const short8*)(
              &smem[cur][4096 + r0 * 64 + ((s * 16 + h * 8) ^ ((r0 & 7) << 3))]);
          o0 = mfma32(vf, bf.s8, o0);
        }
        {
          const int r1 = 32 + lo;
          short8 vf = *(const short8*)(
              &smem[cur][4096 + r1 * 64 + ((s * 16 + h * 8) ^ ((r1 & 7) << 3))]);
          o1 = mfma32(vf, bf.s8, o1);
        }
      }
    }
    __syncthreads();
    cur ^= 1;
  }

  const float rl = 1.0f / ll;
  u16* ep = &smem[0][w * 2048];
#pragma unroll
  for (int rr = 0; rr < 16; ++rr) {
    const int d0 = (rr & 3) + 8 * (rr >> 2) + 4 * h;
    ep[lo * 64 + (d0 ^ ((lo & 7) << 3))] = f2bf(o0[rr] * rl);
    const int d1 = d0 + 32;
    ep[lo * 64 + (d1 ^ ((lo & 7) << 3))] = f2bf(o1[rr] * rl);
  }
  const int hh = bh & 15, b = bh >> 4;
  u16* Ob = O + ((size_t)(b * 2048 + q0w)) * 1024 + hh * 64;
#pragma unroll
  for (int pp = 0; pp < 4; ++pp) {
    const int idx = pp * 64 + l;
    const int row = idx >> 3, c = idx & 7;
    short8 v = *(const short8*)(&ep[row * 64 + ((c * 8) ^ ((row & 7) << 3))]);
    *(short8*)(Ob + (size_t)row * 1024 + c * 8) = v;
  }
}

extern "C" void kernel_launch(void* const* d_in, const int* in_sizes, int n_in,
                              void* d_out, int out_size, void* d_ws,
                              size_t ws_size, hipStream_t stream) {
  const float* x = (const float*)d_in[0];
  const float* w_qkv = (const float*)d_in[1];
  const float* b_qkv = (const float*)d_in[2];
  const float* w_proj = (const float*)d_in[3];
  const float* b_proj = (const float*)d_in[4];
  float* out = (float*)d_out;

  char* ws = (char*)d_ws;
  u16* Xb = (u16*)(ws);                      // [4096,1024] bf16  8 MB
  u16* WqkvT = (u16*)(ws + 8388608);         // [3072,1024] bf16  6 MB
  u16* WprojT = (u16*)(ws + 14680064);       // [1024,1024] bf16  2 MB
  u16* Qw = (u16*)(ws + 16777216);           // [32,2048,64] bf16 8 MB
  u16* Kw = (u16*)(ws + 25165824);           // [32,2048,64] bf16 8 MB
  u16* Vtw = (u16*)(ws + 33554432);          // [32,64,2048] bf16 8 MB
  u16* AttnO = Xb;                           // overlay: Xb dead after GEMM1

  f32_to_bf16_vec<<<2048, 256, 0, stream>>>(x, Xb);
  transpose_f32_to_bf16<<<dim3(48, 16), 256, 0, stream>>>(w_qkv, WqkvT, 1024,
                                                          3072);
  transpose_f32_to_bf16<<<dim3(16, 16), 256, 0, stream>>>(w_proj, WprojT, 1024,
                                                          1024);
  gemm_bt<0><<<dim3(24, 32), 256, 0, stream>>>(Xb, WqkvT, b_qkv, Qw, Kw, Vtw,
                                               nullptr, 4096, 3072, 1024);
  attn_kernel<<<512, 256, 0, stream>>>(Qw, Kw, Vtw, AttnO);
  gemm_bt<1><<<dim3(8, 32), 256, 0, stream>>>(AttnO, WprojT, b_proj, nullptr,
                                              nullptr, nullptr, out, 4096, 1024,
                                              1024);
}

// Round 5
// 169.602 us; speedup vs baseline: 1.5058x; 1.0302x over previous
//
#include <hip/hip_runtime.h>
#include <hip/hip_bf16.h>

typedef unsigned short u16;
typedef __attribute__((ext_vector_type(8))) short short8;
typedef __attribute__((ext_vector_type(4))) float floatx4;
typedef __attribute__((ext_vector_type(16))) float floatx16;

__device__ __forceinline__ u16 f2bf(float f) {
  union { float f; unsigned u; } v; v.f = f;
  unsigned r = v.u + 0x7fffu + ((v.u >> 16) & 1u);
  return (u16)(r >> 16);
}

__device__ __forceinline__ floatx4 mfma16(short8 a, short8 b, floatx4 c) {
  return __builtin_amdgcn_mfma_f32_16x16x32_bf16(a, b, c, 0, 0, 0);
}
__device__ __forceinline__ floatx16 mfma32(short8 a, short8 b, floatx16 c) {
  return __builtin_amdgcn_mfma_f32_32x32x16_bf16(a, b, c, 0, 0, 0);
}

#define AS1 __attribute__((address_space(1)))
#define AS3 __attribute__((address_space(3)))
__device__ __forceinline__ void gload_lds16(const u16* g, u16* l) {
  __builtin_amdgcn_global_load_lds((const AS1 void*)g, (AS3 void*)l, 16, 0, 0);
}

__device__ __forceinline__ unsigned pack2(float a, float b) {
  union { __hip_bfloat162 h; unsigned u; } x;
  x.h = __hip_bfloat162(__float2bfloat16(a), __float2bfloat16(b));
  return x.u;
}

// ---------------- convert: f32 -> bf16, 8 elems/thread ---------------------
__global__ void __launch_bounds__(256) f32_to_bf16_vec(
    const float* __restrict__ in, u16* __restrict__ out) {
  const int i = blockIdx.x * 256 + threadIdx.x;
  const float4* p = (const float4*)in + (size_t)i * 2;
  float4 a = p[0], b = p[1];
  short8 o;
  o[0] = (short)f2bf(a.x); o[1] = (short)f2bf(a.y);
  o[2] = (short)f2bf(a.z); o[3] = (short)f2bf(a.w);
  o[4] = (short)f2bf(b.x); o[5] = (short)f2bf(b.y);
  o[6] = (short)f2bf(b.z); o[7] = (short)f2bf(b.w);
  *(short8*)(out + (size_t)i * 8) = o;
}

// -------- transpose+convert: in f32 [R][C] -> out bf16 [C][R], 64x64 tiles --
__global__ void __launch_bounds__(256) transpose_f32_to_bf16(
    const float* __restrict__ in, u16* __restrict__ out, int R, int C) {
  __shared__ float tile[64][65];
  const int c0 = blockIdx.x * 64, r0 = blockIdx.y * 64;
  const int t = threadIdx.x;
  const int rr = t >> 2, cc = (t & 3) * 16;
  const float* src = in + (size_t)(r0 + rr) * C + (c0 + cc);
  float4 v0 = *(const float4*)(src);
  float4 v1 = *(const float4*)(src + 4);
  float4 v2 = *(const float4*)(src + 8);
  float4 v3 = *(const float4*)(src + 12);
  tile[rr][cc + 0] = v0.x;  tile[rr][cc + 1] = v0.y;
  tile[rr][cc + 2] = v0.z;  tile[rr][cc + 3] = v0.w;
  tile[rr][cc + 4] = v1.x;  tile[rr][cc + 5] = v1.y;
  tile[rr][cc + 6] = v1.z;  tile[rr][cc + 7] = v1.w;
  tile[rr][cc + 8] = v2.x;  tile[rr][cc + 9] = v2.y;
  tile[rr][cc + 10] = v2.z; tile[rr][cc + 11] = v2.w;
  tile[rr][cc + 12] = v3.x; tile[rr][cc + 13] = v3.y;
  tile[rr][cc + 14] = v3.z; tile[rr][cc + 15] = v3.w;
  __syncthreads();
  short8 w0, w1;
#pragma unroll
  for (int i = 0; i < 8; ++i) {
    w0[i] = (short)f2bf(tile[cc + i][rr]);
    w1[i] = (short)f2bf(tile[cc + 8 + i][rr]);
  }
  u16* dst = out + (size_t)(c0 + rr) * R + (r0 + cc);
  *(short8*)dst = w0;
  *(short8*)(dst + 8) = w1;
}

// ---------------- GEMM: C[M,N] = A[M,K] * Bt[N,K]^T + bias -----------------
// 2-phase double-buffered LDS, k-chunk-major layout [4][128][8] (conflict-free
// ds_read_b128: each 16-lane fragment group reads 256 B contiguous).
// Wave w stages k-chunk w for all 128 rows (global src per-lane, LDS dest
// wave-linear). One barrier per K-step; STAGE(t+1) overlaps compute(t).
template <int EPI>
__global__ void __launch_bounds__(256, 2) gemm_bt(
    const u16* __restrict__ A, const u16* __restrict__ Bt,
    const float* __restrict__ bias, u16* __restrict__ O0,
    u16* __restrict__ O1, u16* __restrict__ O2, float* __restrict__ Of,
    int M, int N, int K) {
  __shared__ u16 As[2][4096];  // [buf][kc*1024 + row*8]
  __shared__ u16 Bs[2][4096];
  const int t = threadIdx.x, w = t >> 6, l = t & 63;
  const int lo = l & 15, g = l >> 4;
  const int wr = w >> 1, wc = w & 1;
  const int m0 = blockIdx.y * 128, n0 = blockIdx.x * 128;
  // staging: wave w covers k-chunk w (8 u16), rows l and 64+l
  const u16* Ag = A + (size_t)(m0 + l) * K + w * 8;
  const u16* Bg = Bt + (size_t)(n0 + l) * K + w * 8;

  floatx4 acc[4][4] = {};
  const int NT = K >> 5;

#define STAGE_G(buf, k0)                                          \
  do {                                                            \
    gload_lds16(Ag + (k0), &As[buf][w * 1024]);                   \
    gload_lds16(Ag + (size_t)64 * K + (k0), &As[buf][w * 1024 + 512]); \
    gload_lds16(Bg + (k0), &Bs[buf][w * 1024]);                   \
    gload_lds16(Bg + (size_t)64 * K + (k0), &Bs[buf][w * 1024 + 512]); \
  } while (0)

  STAGE_G(0, 0);
  __syncthreads();
  int cur = 0;
  for (int kt = 0; kt < NT; ++kt) {
    if (kt + 1 < NT) STAGE_G(cur ^ 1, (kt + 1) * 32);
    short8 af[4], bff[4];
#pragma unroll
    for (int m = 0; m < 4; ++m)
      af[m] = *(const short8*)(&As[cur][g * 1024 + (wr * 64 + m * 16 + lo) * 8]);
#pragma unroll
    for (int n = 0; n < 4; ++n)
      bff[n] = *(const short8*)(&Bs[cur][g * 1024 + (wc * 64 + n * 16 + lo) * 8]);
#pragma unroll
    for (int m = 0; m < 4; ++m)
#pragma unroll
      for (int n = 0; n < 4; ++n) acc[m][n] = mfma16(af[m], bff[n], acc[m][n]);
    __syncthreads();
    cur ^= 1;
  }
#undef STAGE_G

#pragma unroll
  for (int m = 0; m < 4; ++m) {
    const int row_base = m0 + wr * 64 + m * 16 + g * 4;
#pragma unroll
    for (int n = 0; n < 4; ++n) {
      const int col = n0 + wc * 64 + n * 16 + lo;
      const float bv = bias[col];
#pragma unroll
      for (int j = 0; j < 4; ++j) {
        const int r = row_base + j;
        const float v = acc[m][n][j] + bv;
        if (EPI == 0) {
          const u16 h = f2bf(v);
          const int b = r >> 11, s = r & 2047;
          int c = col;
          if (c < 1024) {
            const int hh = c >> 6, d = c & 63;
            O0[(((size_t)(b * 16 + hh)) * 2048 + s) * 64 + d] = h;
          } else if (c < 2048) {
            c -= 1024;
            const int hh = c >> 6, d = c & 63;
            O1[(((size_t)(b * 16 + hh)) * 2048 + s) * 64 + d] = h;
          } else {
            c -= 2048;
            const int hh = c >> 6, d = c & 63;
            O2[(((size_t)(b * 16 + hh)) * 64 + d) * 2048 + s] = h;
          }
        } else {
          Of[(size_t)r * N + col] = v;
        }
      }
    }
  }
}

// ---------------- causal flash attention (4-wave, swapped 32x32) ----------
// Q,K: [B*H, S, 64] bf16; Vt: [B*H, 64, S] bf16; O: [B, S, 1024] bf16
__global__ void __launch_bounds__(256, 2) attn_kernel(
    const u16* __restrict__ Q, const u16* __restrict__ K,
    const u16* __restrict__ Vt, u16* __restrict__ O) {
  const int S = 2048;
  __shared__ u16 smem[2][8192];  // per buf: K tile [64][64] | V tile [64][64]
  const int t = threadIdx.x, w = t >> 6, l = t & 63;
  const int lo = l & 31, h = l >> 5;
  const int fid = blockIdx.x;
  const int half = fid >> 8, rdec = fid & 255;
  const int bh = half * 16 + (rdec >> 4);
  const int qb = half ? (15 - (rdec & 15)) : (rdec & 15);
  const int q0w = qb * 128 + w * 32;
  const int qmax = q0w + 31;
  const int qabs = q0w + lo;
  const u16* Qb = Q + (size_t)bh * S * 64;
  const u16* Kb = K + (size_t)bh * S * 64;
  const u16* Vb = Vt + (size_t)bh * 64 * S;

  short8 qf[4];
#pragma unroll
  for (int ks = 0; ks < 4; ++ks)
    qf[ks] = *(const short8*)(Qb + (size_t)(q0w + lo) * 64 + ks * 16 + h * 8);

  floatx16 o0 = {}, o1 = {};
  float m2 = -1e30f, ll = 0.f;

  auto STAGE = [&](int buf, int kv0) {
#pragma unroll
    for (int i = 0; i < 2; ++i) {
      const int idx = i * 256 + t;
      const int rw = idx >> 3;
      const int cg = (idx & 7) ^ (rw & 7);  // pre-swizzled global chunk
      gload_lds16(Kb + (size_t)(kv0 + rw) * 64 + cg * 8,
                  &smem[buf][i * 2048 + w * 512]);
      gload_lds16(Vb + (size_t)rw * S + kv0 + cg * 8,
                  &smem[buf][4096 + i * 2048 + w * 512]);
    }
  };

  const int T = 2 * (qb + 1);
  STAGE(0, 0);
  __syncthreads();
  int cur = 0;
  for (int tt = 0; tt < T; ++tt) {
    const int kv0 = tt * 64;
    if (tt + 1 < T) STAGE(cur ^ 1, (tt + 1) * 64);
    if (kv0 <= qmax) {
      floatx16 st0 = {}, st1 = {};
#pragma unroll
      for (int ks = 0; ks < 4; ++ks) {
        const int r0 = lo;
        short8 kf0 = *(const short8*)(
            &smem[cur][r0 * 64 + ((ks * 16 + h * 8) ^ ((r0 & 7) << 3))]);
        st0 = mfma32(kf0, qf[ks], st0);
        const int r1 = 32 + lo;
        short8 kf1 = *(const short8*)(
            &smem[cur][r1 * 64 + ((ks * 16 + h * 8) ^ ((r1 & 7) << 3))]);
        st1 = mfma32(kf1, qf[ks], st1);
      }
      const bool diag = (kv0 + 63 > q0w);
      float p[2][16];
      float tmax = -1e30f;
#pragma unroll
      for (int rr = 0; rr < 16; ++rr) {
        float v0 = st0[rr] * 0.125f;
        float v1 = st1[rr] * 0.125f;
        if (diag) {
          const int kvr = kv0 + (rr & 3) + 8 * (rr >> 2) + 4 * h;
          if (kvr > qabs) v0 = -1e30f;
          if (kvr + 32 > qabs) v1 = -1e30f;
        }
        p[0][rr] = v0;
        p[1][rr] = v1;
        tmax = fmaxf(tmax, fmaxf(v0, v1));
      }
      tmax = fmaxf(tmax, __shfl_xor(tmax, 32));
      const float mnew = fmaxf(m2, tmax);
      const float corr = __expf(m2 - mnew);
      m2 = mnew;
      float tsum = 0.f;
#pragma unroll
      for (int nt = 0; nt < 2; ++nt)
#pragma unroll
        for (int rr = 0; rr < 16; ++rr) {
          const float e = __expf(p[nt][rr] - m2);
          p[nt][rr] = e;
          tsum += e;
        }
      tsum += __shfl_xor(tsum, 32);
      ll = ll * corr + tsum;
      o0 = o0 * corr;
      o1 = o1 * corr;
#pragma unroll
      for (int s = 0; s < 4; ++s) {
        const int ts = s >> 1, rb = (s & 1) * 8;
        const unsigned wA = pack2(p[ts][rb + 0], p[ts][rb + 1]);
        const unsigned wB = pack2(p[ts][rb + 2], p[ts][rb + 3]);
        const unsigned wC = pack2(p[ts][rb + 4], p[ts][rb + 5]);
        const unsigned wD = pack2(p[ts][rb + 6], p[ts][rb + 7]);
        const unsigned sA = (unsigned)__shfl_xor((int)wA, 32);
        const unsigned sB = (unsigned)__shfl_xor((int)wB, 32);
        const unsigned sC = (unsigned)__shfl_xor((int)wC, 32);
        const unsigned sD = (unsigned)__shfl_xor((int)wD, 32);
        union { unsigned u[4]; short8 s8; } bf;
        bf.u[0] = h ? sC : wA;
        bf.u[1] = h ? sD : wB;
        bf.u[2] = h ? wC : sA;
        bf.u[3] = h ? wD : sB;
        {
          const int r0 = lo;
          short8 vf = *(const short8*)(
              &smem[cur][4096 + r0 * 64 + ((s * 16 + h * 8) ^ ((r0 & 7) << 3))]);
          o0 = mfma32(vf, bf.s8, o0);
        }
        {
          const int r1 = 32 + lo;
          short8 vf = *(const short8*)(
              &smem[cur][4096 + r1 * 64 + ((s * 16 + h * 8) ^ ((r1 & 7) << 3))]);
          o1 = mfma32(vf, bf.s8, o1);
        }
      }
    }
    __syncthreads();
    cur ^= 1;
  }

  const float rl = 1.0f / ll;
  u16* ep = &smem[0][w * 2048];
#pragma unroll
  for (int rr = 0; rr < 16; ++rr) {
    const int d0 = (rr & 3) + 8 * (rr >> 2) + 4 * h;
    ep[lo * 64 + (d0 ^ ((lo & 7) << 3))] = f2bf(o0[rr] * rl);
    const int d1 = d0 + 32;
    ep[lo * 64 + (d1 ^ ((lo & 7) << 3))] = f2bf(o1[rr] * rl);
  }
  const int hh = bh & 15, b = bh >> 4;
  u16* Ob = O + ((size_t)(b * 2048 + q0w)) * 1024 + hh * 64;
#pragma unroll
  for (int pp = 0; pp < 4; ++pp) {
    const int idx = pp * 64 + l;
    const int row = idx >> 3, c = idx & 7;
    short8 v = *(const short8*)(&ep[row * 64 + ((c * 8) ^ ((row & 7) << 3))]);
    *(short8*)(Ob + (size_t)row * 1024 + c * 8) = v;
  }
}

extern "C" void kernel_launch(void* const* d_in, const int* in_sizes, int n_in,
                              void* d_out, int out_size, void* d_ws,
                              size_t ws_size, hipStream_t stream) {
  const float* x = (const float*)d_in[0];
  const float* w_qkv = (const float*)d_in[1];
  const float* b_qkv = (const float*)d_in[2];
  const float* w_proj = (const float*)d_in[3];
  const float* b_proj = (const float*)d_in[4];
  float* out = (float*)d_out;

  char* ws = (char*)d_ws;
  u16* Xb = (u16*)(ws);                      // [4096,1024] bf16  8 MB
  u16* WqkvT = (u16*)(ws + 8388608);         // [3072,1024] bf16  6 MB
  u16* WprojT = (u16*)(ws + 14680064);       // [1024,1024] bf16  2 MB
  u16* Qw = (u16*)(ws + 16777216);           // [32,2048,64] bf16 8 MB
  u16* Kw = (u16*)(ws + 25165824);           // [32,2048,64] bf16 8 MB
  u16* Vtw = (u16*)(ws + 33554432);          // [32,64,2048] bf16 8 MB
  u16* AttnO = Xb;                           // overlay: Xb dead after GEMM1

  f32_to_bf16_vec<<<2048, 256, 0, stream>>>(x, Xb);
  transpose_f32_to_bf16<<<dim3(48, 16), 256, 0, stream>>>(w_qkv, WqkvT, 1024,
                                                          3072);
  transpose_f32_to_bf16<<<dim3(16, 16), 256, 0, stream>>>(w_proj, WprojT, 1024,
                                                          1024);
  gemm_bt<0><<<dim3(24, 32), 256, 0, stream>>>(Xb, WqkvT, b_qkv, Qw, Kw, Vtw,
                                               nullptr, 4096, 3072, 1024);
  attn_kernel<<<512, 256, 0, stream>>>(Qw, Kw, Vtw, AttnO);
  gemm_bt<1><<<dim3(8, 32), 256, 0, stream>>>(AttnO, WprojT, b_proj, nullptr,
                                              nullptr, nullptr, out, 4096, 1024,
                                              1024);
}

// Round 6
// 154.807 us; speedup vs baseline: 1.6498x; 1.0956x over previous
//
#include <hip/hip_runtime.h>
#include <hip/hip_bf16.h>

typedef unsigned short u16;
typedef __attribute__((ext_vector_type(8))) short short8;
typedef __attribute__((ext_vector_type(4))) float floatx4;
typedef __attribute__((ext_vector_type(16))) float floatx16;

__device__ __forceinline__ u16 f2bf(float f) {
  union { float f; unsigned u; } v; v.f = f;
  unsigned r = v.u + 0x7fffu + ((v.u >> 16) & 1u);
  return (u16)(r >> 16);
}

__device__ __forceinline__ floatx4 mfma16(short8 a, short8 b, floatx4 c) {
  return __builtin_amdgcn_mfma_f32_16x16x32_bf16(a, b, c, 0, 0, 0);
}
__device__ __forceinline__ floatx16 mfma32(short8 a, short8 b, floatx16 c) {
  return __builtin_amdgcn_mfma_f32_32x32x16_bf16(a, b, c, 0, 0, 0);
}

#define AS1 __attribute__((address_space(1)))
#define AS3 __attribute__((address_space(3)))
__device__ __forceinline__ void gload_lds16(const u16* g, u16* l) {
  __builtin_amdgcn_global_load_lds((const AS1 void*)g, (AS3 void*)l, 16, 0, 0);
}

__device__ __forceinline__ unsigned pack2(float a, float b) {
  union { __hip_bfloat162 h; unsigned u; } x;
  x.h = __hip_bfloat162(__float2bfloat16(a), __float2bfloat16(b));
  return x.u;
}

__device__ __forceinline__ float fexp2(float x) {
#if __has_builtin(__builtin_amdgcn_exp2f)
  return __builtin_amdgcn_exp2f(x);
#else
  return exp2f(x);
#endif
}

// Q is pre-scaled by 1/sqrt(64) * log2(e) so softmax runs in exp2 domain.
#define QSCALE 0.18033688f

// ---------------- convert: f32 -> bf16, 8 elems/thread ---------------------
__global__ void __launch_bounds__(256) f32_to_bf16_vec(
    const float* __restrict__ in, u16* __restrict__ out) {
  const int i = blockIdx.x * 256 + threadIdx.x;
  const float4* p = (const float4*)in + (size_t)i * 2;
  float4 a = p[0], b = p[1];
  short8 o;
  o[0] = (short)f2bf(a.x); o[1] = (short)f2bf(a.y);
  o[2] = (short)f2bf(a.z); o[3] = (short)f2bf(a.w);
  o[4] = (short)f2bf(b.x); o[5] = (short)f2bf(b.y);
  o[6] = (short)f2bf(b.z); o[7] = (short)f2bf(b.w);
  *(short8*)(out + (size_t)i * 8) = o;
}

// -------- transpose+convert: in f32 [R][C] -> out bf16 [C][R], 64x64 tiles --
__global__ void __launch_bounds__(256) transpose_f32_to_bf16(
    const float* __restrict__ in, u16* __restrict__ out, int R, int C) {
  __shared__ float tile[64][65];
  const int c0 = blockIdx.x * 64, r0 = blockIdx.y * 64;
  const int t = threadIdx.x;
  const int rr = t >> 2, cc = (t & 3) * 16;
  const float* src = in + (size_t)(r0 + rr) * C + (c0 + cc);
  float4 v0 = *(const float4*)(src);
  float4 v1 = *(const float4*)(src + 4);
  float4 v2 = *(const float4*)(src + 8);
  float4 v3 = *(const float4*)(src + 12);
  tile[rr][cc + 0] = v0.x;  tile[rr][cc + 1] = v0.y;
  tile[rr][cc + 2] = v0.z;  tile[rr][cc + 3] = v0.w;
  tile[rr][cc + 4] = v1.x;  tile[rr][cc + 5] = v1.y;
  tile[rr][cc + 6] = v1.z;  tile[rr][cc + 7] = v1.w;
  tile[rr][cc + 8] = v2.x;  tile[rr][cc + 9] = v2.y;
  tile[rr][cc + 10] = v2.z; tile[rr][cc + 11] = v2.w;
  tile[rr][cc + 12] = v3.x; tile[rr][cc + 13] = v3.y;
  tile[rr][cc + 14] = v3.z; tile[rr][cc + 15] = v3.w;
  __syncthreads();
  short8 w0, w1;
#pragma unroll
  for (int i = 0; i < 8; ++i) {
    w0[i] = (short)f2bf(tile[cc + i][rr]);
    w1[i] = (short)f2bf(tile[cc + 8 + i][rr]);
  }
  u16* dst = out + (size_t)(c0 + rr) * R + (r0 + cc);
  *(short8*)dst = w0;
  *(short8*)(dst + 8) = w1;
}

// ---------------- GEMM: C[M,N] = A[M,K] * Bt[N,K]^T + bias -----------------
// 2-phase double-buffered LDS, k-chunk-major layout [4][128][8] (conflict-free
// ds_read_b128). EPI==0 scatters Q (pre-scaled by QSCALE), K, V^T; EPI==1
// writes f32.
template <int EPI>
__global__ void __launch_bounds__(256, 3) gemm_bt(
    const u16* __restrict__ A, const u16* __restrict__ Bt,
    const float* __restrict__ bias, u16* __restrict__ O0,
    u16* __restrict__ O1, u16* __restrict__ O2, float* __restrict__ Of,
    int M, int N, int K) {
  __shared__ u16 As[2][4096];  // [buf][kc*1024 + row*8]
  __shared__ u16 Bs[2][4096];
  const int t = threadIdx.x, w = t >> 6, l = t & 63;
  const int lo = l & 15, g = l >> 4;
  const int wr = w >> 1, wc = w & 1;
  const int m0 = blockIdx.y * 128, n0 = blockIdx.x * 128;
  const u16* Ag = A + (size_t)(m0 + l) * K + w * 8;
  const u16* Bg = Bt + (size_t)(n0 + l) * K + w * 8;

  floatx4 acc[4][4] = {};
  const int NT = K >> 5;

#define STAGE_G(buf, k0)                                          \
  do {                                                            \
    gload_lds16(Ag + (k0), &As[buf][w * 1024]);                   \
    gload_lds16(Ag + (size_t)64 * K + (k0), &As[buf][w * 1024 + 512]); \
    gload_lds16(Bg + (k0), &Bs[buf][w * 1024]);                   \
    gload_lds16(Bg + (size_t)64 * K + (k0), &Bs[buf][w * 1024 + 512]); \
  } while (0)

  STAGE_G(0, 0);
  __syncthreads();
  int cur = 0;
  for (int kt = 0; kt < NT; ++kt) {
    if (kt + 1 < NT) STAGE_G(cur ^ 1, (kt + 1) * 32);
    short8 af[4], bff[4];
#pragma unroll
    for (int m = 0; m < 4; ++m)
      af[m] = *(const short8*)(&As[cur][g * 1024 + (wr * 64 + m * 16 + lo) * 8]);
#pragma unroll
    for (int n = 0; n < 4; ++n)
      bff[n] = *(const short8*)(&Bs[cur][g * 1024 + (wc * 64 + n * 16 + lo) * 8]);
#pragma unroll
    for (int m = 0; m < 4; ++m)
#pragma unroll
      for (int n = 0; n < 4; ++n) acc[m][n] = mfma16(af[m], bff[n], acc[m][n]);
    __syncthreads();
    cur ^= 1;
  }
#undef STAGE_G

#pragma unroll
  for (int m = 0; m < 4; ++m) {
    const int row_base = m0 + wr * 64 + m * 16 + g * 4;
#pragma unroll
    for (int n = 0; n < 4; ++n) {
      const int col = n0 + wc * 64 + n * 16 + lo;
      const float bv = bias[col];
#pragma unroll
      for (int j = 0; j < 4; ++j) {
        const int r = row_base + j;
        const float v = acc[m][n][j] + bv;
        if (EPI == 0) {
          const int b = r >> 11, s = r & 2047;
          int c = col;
          if (c < 1024) {
            const int hh = c >> 6, d = c & 63;
            O0[(((size_t)(b * 16 + hh)) * 2048 + s) * 64 + d] = f2bf(v * QSCALE);
          } else if (c < 2048) {
            c -= 1024;
            const int hh = c >> 6, d = c & 63;
            O1[(((size_t)(b * 16 + hh)) * 2048 + s) * 64 + d] = f2bf(v);
          } else {
            c -= 2048;
            const int hh = c >> 6, d = c & 63;
            O2[(((size_t)(b * 16 + hh)) * 64 + d) * 2048 + s] = f2bf(v);
          }
        } else {
          Of[(size_t)r * N + col] = v;
        }
      }
    }
  }
}

// ---------------- causal flash attention (4-wave, swapped 32x32) ----------
// Q (pre-scaled): [B*H, S, 64] bf16; K: same; Vt: [B*H, 64, S]; O: [B,S,1024]
__global__ void __launch_bounds__(256, 2) attn_kernel(
    const u16* __restrict__ Q, const u16* __restrict__ K,
    const u16* __restrict__ Vt, u16* __restrict__ O) {
  const int S = 2048;
  __shared__ u16 smem[2][8192];  // per buf: K tile [64][64] | V tile [64][64]
  const int t = threadIdx.x, w = t >> 6, l = t & 63;
  const int lo = l & 31, h = l >> 5;
  const int fid = blockIdx.x;
  const int half = fid >> 8, rdec = fid & 255;
  const int bh = half * 16 + (rdec >> 4);
  const int qb = half ? (15 - (rdec & 15)) : (rdec & 15);
  const int q0w = qb * 128 + w * 32;
  const int qmax = q0w + 31;
  const int qabs = q0w + lo;
  const u16* Qb = Q + (size_t)bh * S * 64;
  const u16* Kb = K + (size_t)bh * S * 64;
  const u16* Vb = Vt + (size_t)bh * 64 * S;

  short8 qf[4];
#pragma unroll
  for (int ks = 0; ks < 4; ++ks)
    qf[ks] = *(const short8*)(Qb + (size_t)(q0w + lo) * 64 + ks * 16 + h * 8);

  floatx16 o0 = {}, o1 = {};
  float m2 = -1e30f, ll = 0.f;

  auto STAGE = [&](int buf, int kv0) {
#pragma unroll
    for (int i = 0; i < 2; ++i) {
      const int idx = i * 256 + t;
      const int rw = idx >> 3;
      const int cg = (idx & 7) ^ (rw & 7);  // pre-swizzled global chunk
      gload_lds16(Kb + (size_t)(kv0 + rw) * 64 + cg * 8,
                  &smem[buf][i * 2048 + w * 512]);
      gload_lds16(Vb + (size_t)rw * S + kv0 + cg * 8,
                  &smem[buf][4096 + i * 2048 + w * 512]);
    }
  };

  const int T = 2 * (qb + 1);
  STAGE(0, 0);
  __syncthreads();
  int cur = 0;
  for (int tt = 0; tt < T; ++tt) {
    const int kv0 = tt * 64;
    if (tt + 1 < T) STAGE(cur ^ 1, (tt + 1) * 64);
    if (kv0 <= qmax) {
      floatx16 st0 = {}, st1 = {};
#pragma unroll
      for (int ks = 0; ks < 4; ++ks) {
        const int r0 = lo;
        short8 kf0 = *(const short8*)(
            &smem[cur][r0 * 64 + ((ks * 16 + h * 8) ^ ((r0 & 7) << 3))]);
        st0 = mfma32(kf0, qf[ks], st0);
        const int r1 = 32 + lo;
        short8 kf1 = *(const short8*)(
            &smem[cur][r1 * 64 + ((ks * 16 + h * 8) ^ ((r1 & 7) << 3))]);
        st1 = mfma32(kf1, qf[ks], st1);
      }
      const bool diag = (kv0 + 63 > q0w);
      float p[2][16];
      float tmax = -1e30f;
#pragma unroll
      for (int rr = 0; rr < 16; ++rr) {
        float v0 = st0[rr];
        float v1 = st1[rr];
        if (diag) {
          const int kvr = kv0 + (rr & 3) + 8 * (rr >> 2) + 4 * h;
          if (kvr > qabs) v0 = -1e30f;
          if (kvr + 32 > qabs) v1 = -1e30f;
        }
        p[0][rr] = v0;
        p[1][rr] = v1;
        tmax = fmaxf(tmax, fmaxf(v0, v1));
      }
      tmax = fmaxf(tmax, __shfl_xor(tmax, 32));
      // defer-max: only rescale when the running max grew by > 8 (log2 domain)
      if (!__all(tmax <= m2 + 8.0f)) {
        const float mnew = fmaxf(m2, tmax);
        const float corr = fexp2(m2 - mnew);
        m2 = mnew;
        ll *= corr;
        o0 = o0 * corr;
        o1 = o1 * corr;
      }
      float tsum = 0.f;
#pragma unroll
      for (int nt = 0; nt < 2; ++nt)
#pragma unroll
        for (int rr = 0; rr < 16; ++rr) {
          const float e = fexp2(p[nt][rr] - m2);
          p[nt][rr] = e;
          tsum += e;
        }
      tsum += __shfl_xor(tsum, 32);
      ll += tsum;
#pragma unroll
      for (int s = 0; s < 4; ++s) {
        const int ts = s >> 1, rb = (s & 1) * 8;
        const unsigned wA = pack2(p[ts][rb + 0], p[ts][rb + 1]);
        const unsigned wB = pack2(p[ts][rb + 2], p[ts][rb + 3]);
        const unsigned wC = pack2(p[ts][rb + 4], p[ts][rb + 5]);
        const unsigned wD = pack2(p[ts][rb + 6], p[ts][rb + 7]);
        union { unsigned u[4]; short8 s8; } bf;
#if __has_builtin(__builtin_amdgcn_permlane32_swap)
        auto r02 = __builtin_amdgcn_permlane32_swap((int)wA, (int)wC, false, false);
        auto r13 = __builtin_amdgcn_permlane32_swap((int)wB, (int)wD, false, false);
        bf.u[0] = (unsigned)r02[0];
        bf.u[1] = (unsigned)r13[0];
        bf.u[2] = (unsigned)r02[1];
        bf.u[3] = (unsigned)r13[1];
#else
        const unsigned sA = (unsigned)__shfl_xor((int)wA, 32);
        const unsigned sB = (unsigned)__shfl_xor((int)wB, 32);
        const unsigned sC = (unsigned)__shfl_xor((int)wC, 32);
        const unsigned sD = (unsigned)__shfl_xor((int)wD, 32);
        bf.u[0] = h ? sC : wA;
        bf.u[1] = h ? sD : wB;
        bf.u[2] = h ? wC : sA;
        bf.u[3] = h ? wD : sB;
#endif
        {
          const int r0 = lo;
          short8 vf = *(const short8*)(
              &smem[cur][4096 + r0 * 64 + ((s * 16 + h * 8) ^ ((r0 & 7) << 3))]);
          o0 = mfma32(vf, bf.s8, o0);
        }
        {
          const int r1 = 32 + lo;
          short8 vf = *(const short8*)(
              &smem[cur][4096 + r1 * 64 + ((s * 16 + h * 8) ^ ((r1 & 7) << 3))]);
          o1 = mfma32(vf, bf.s8, o1);
        }
      }
    }
    __syncthreads();
    cur ^= 1;
  }

  const float rl = 1.0f / ll;
  u16* ep = &smem[0][w * 2048];
#pragma unroll
  for (int rr = 0; rr < 16; ++rr) {
    const int d0 = (rr & 3) + 8 * (rr >> 2) + 4 * h;
    ep[lo * 64 + (d0 ^ ((lo & 7) << 3))] = f2bf(o0[rr] * rl);
    const int d1 = d0 + 32;
    ep[lo * 64 + (d1 ^ ((lo & 7) << 3))] = f2bf(o1[rr] * rl);
  }
  const int hh = bh & 15, b = bh >> 4;
  u16* Ob = O + ((size_t)(b * 2048 + q0w)) * 1024 + hh * 64;
#pragma unroll
  for (int pp = 0; pp < 4; ++pp) {
    const int idx = pp * 64 + l;
    const int row = idx >> 3, c = idx & 7;
    short8 v = *(const short8*)(&ep[row * 64 + ((c * 8) ^ ((row & 7) << 3))]);
    *(short8*)(Ob + (size_t)row * 1024 + c * 8) = v;
  }
}

extern "C" void kernel_launch(void* const* d_in, const int* in_sizes, int n_in,
                              void* d_out, int out_size, void* d_ws,
                              size_t ws_size, hipStream_t stream) {
  const float* x = (const float*)d_in[0];
  const float* w_qkv = (const float*)d_in[1];
  const float* b_qkv = (const float*)d_in[2];
  const float* w_proj = (const float*)d_in[3];
  const float* b_proj = (const float*)d_in[4];
  float* out = (float*)d_out;

  char* ws = (char*)d_ws;
  u16* Xb = (u16*)(ws);                      // [4096,1024] bf16  8 MB
  u16* WqkvT = (u16*)(ws + 8388608);         // [3072,1024] bf16  6 MB
  u16* WprojT = (u16*)(ws + 14680064);       // [1024,1024] bf16  2 MB
  u16* Qw = (u16*)(ws + 16777216);           // [32,2048,64] bf16 8 MB
  u16* Kw = (u16*)(ws + 25165824);           // [32,2048,64] bf16 8 MB
  u16* Vtw = (u16*)(ws + 33554432);          // [32,64,2048] bf16 8 MB
  u16* AttnO = Xb;                           // overlay: Xb dead after GEMM1

  f32_to_bf16_vec<<<2048, 256, 0, stream>>>(x, Xb);
  transpose_f32_to_bf16<<<dim3(48, 16), 256, 0, stream>>>(w_qkv, WqkvT, 1024,
                                                          3072);
  transpose_f32_to_bf16<<<dim3(16, 16), 256, 0, stream>>>(w_proj, WprojT, 1024,
                                                          1024);
  gemm_bt<0><<<dim3(24, 32), 256, 0, stream>>>(Xb, WqkvT, b_qkv, Qw, Kw, Vtw,
                                               nullptr, 4096, 3072, 1024);
  attn_kernel<<<512, 256, 0, stream>>>(Qw, Kw, Vtw, AttnO);
  gemm_bt<1><<<dim3(8, 32), 256, 0, stream>>>(AttnO, WprojT, b_proj, nullptr,
                                              nullptr, nullptr, out, 4096, 1024,
                                              1024);
}